// Round 17
// baseline (18332.204 us; speedup 1.0000x reference)
//
#include <hip/hip_runtime.h>
#include <stdint.h>

// CondDecoder: B=256, T=128, V=64, L=128, H=512, E=32, NL=3, IN0=161 (pad 192)
// (t,b)-major activations: row m = t*256 + b.
// R17: BLOCK-LOCAL recurrence. 16 blocks x 16 batch rows; each block keeps h in
// its own LDS and streams the full 1.5MB Whh from L2 every step. ZERO cross-block
// communication (no atomics/flags/MALL RTTs — the R12-R15 ~2.4us/step protocol
// floor is gone). Per-XCD distinct weight bytes = 1.5MB < 4MB L2 under ANY
// workgroup->XCD mapping (R16's mega died on an assumed mapping; this is robust).
// gi = kgemm output, prefetched to LDS via global_load_lds at step start and
// consumed after the MFMA phase (latency hidden under ~1900cy of MFMA).
#define TT 128
#define G3 1536

typedef __attribute__((ext_vector_type(8))) short bf16x8;
typedef __attribute__((ext_vector_type(4))) float f32x4;

__device__ __forceinline__ unsigned short f2bf(float f){
  unsigned int x = __builtin_bit_cast(unsigned int, f);
  x = x + 0x7fffu + ((x >> 16) & 1u);
  return (unsigned short)(x >> 16);
}
__device__ __forceinline__ float bf2f(unsigned short u){
  unsigned int x = ((unsigned int)u) << 16;
  return __builtin_bit_cast(float, x);
}
__device__ __forceinline__ void gl_lds16(const void* g, void* l){
  __builtin_amdgcn_global_load_lds((const __attribute__((address_space(1))) unsigned int*)g,
                                   (__attribute__((address_space(3))) unsigned int*)l, 16, 0, 0);
}

// ---- fused prep: Wih1/2 conv + 3x Whh fragment-permute (wave-stream order) +
//      Wih0 pad + fcW^T.  grid 13440 x 256.
__global__ __launch_bounds__(256) void kprep(
    const float* __restrict__ Wih1f, const float* __restrict__ Wih2f,
    unsigned short* __restrict__ wih1b, unsigned short* __restrict__ wih2b,
    const float* __restrict__ Whh0f, const float* __restrict__ Whh1f,
    const float* __restrict__ Whh2f,
    unsigned short* __restrict__ whp0, unsigned short* __restrict__ whp1,
    unsigned short* __restrict__ whp2,
    const float* __restrict__ Wih0f, unsigned short* __restrict__ wih0p,
    const float* __restrict__ fcw, float* __restrict__ fcwt){
  int bx = blockIdx.x, tid = threadIdx.x;
  if (bx < 3072){
    int i = bx*256 + tid;                     // Wih1/2 -> bf16 flat
    wih1b[i] = f2bf(Wih1f[i]); wih2b[i] = f2bf(Wih2f[i]);
  } else if (bx < 12288){
    int j = bx - 3072;                        // Whh -> per-wave-contiguous frags
    int layer = j / 3072;                     // i = (((wv*24 + g*8 + ct)*16 + ks)*64 + lane)*8 + e
    int i = (j - layer*3072)*256 + tid;
    const float* src = (layer == 0) ? Whh0f : ((layer == 1) ? Whh1f : Whh2f);
    unsigned short* dst = (layer == 0) ? whp0 : ((layer == 1) ? whp1 : whp2);
    int e = i & 7, lane = (i >> 3) & 63, ks = (i >> 9) & 15, rest = i >> 13;
    int wv = rest / 24, sub = rest % 24;
    int g = sub >> 3, ct = sub & 7;
    int gcol = wv*128 + ct*16 + (lane & 15);
    int k = ks*32 + (lane >> 4)*8 + e;
    dst[i] = f2bf(src[(size_t)(g*512 + gcol)*512 + k]);
  } else {
    int i = (bx - 12288)*256 + tid;           // Wih0 pad 161->192; fcW transpose
    if (i < 1536*192){
      int n = i / 192, k = i - n*192;
      wih0p[i] = (k < 161) ? f2bf(Wih0f[n*161 + k]) : (unsigned short)0;
    }
    if (i < 512*64){
      int k = i >> 6, v = i & 63;
      fcwt[i] = fcw[v*512 + k];
    }
  }
}

// ---- prep: x0 [32768][192] bf16 in (t,b) order
__global__ __launch_bounds__(192) void kx0(const float* __restrict__ latent,
    const float* __restrict__ enth, const int* __restrict__ inp,
    const float* __restrict__ emb, unsigned short* __restrict__ x0){
  int c = threadIdx.x;
  #pragma unroll
  for (int mr = 0; mr < 4; ++mr){
    int m = blockIdx.x*4 + mr;       // grid 8192
    int b = m & 255, t = m >> 8;
    float v;
    if (c < 128) v = latent[b*128 + c];
    else if (c < 160){
      int tok = (t == 0) ? 0 : inp[b*128 + t - 1];
      v = emb[tok*32 + (c - 128)];
    }
    else if (c == 160) v = enth[b];
    else v = 0.f;
    x0[(size_t)m*192 + c] = f2bf(v);
  }
}

// ---- bf16 MFMA GEMM: C[m][n] = A[m][K] @ Bt[n][K]^T + bias[n]; bf16 out
__global__ __launch_bounds__(256) void kgemm(const unsigned short* __restrict__ A,
    const unsigned short* __restrict__ Bt, const float* __restrict__ bias,
    unsigned short* __restrict__ C, int K){
  __shared__ __align__(16) unsigned short As[128*32];
  __shared__ __align__(16) unsigned short Bs[128*32];
  const int m0 = blockIdx.y*128, n0 = blockIdx.x*128;
  const int wv = threadIdx.x >> 6, lane = threadIdx.x & 63;
  const int woffM = (wv >> 1)*64, woffN = (wv & 1)*64;
  f32x4 acc[4][4] = {};
  for (int k0 = 0; k0 < K; k0 += 32){
    __syncthreads();
    #pragma unroll
    for (int i = 0; i < 4; ++i){
      int e = wv*4 + i;
      int ee = e & 7;
      int row = ee*16 + (lane >> 2);
      if (e < 8) gl_lds16(A  + (size_t)(m0+row)*K + k0 + (lane & 3)*8, (void*)&As[ee*512]);
      else       gl_lds16(Bt + (size_t)(n0+row)*K + k0 + (lane & 3)*8, (void*)&Bs[ee*512]);
    }
    __syncthreads();
    bf16x8 af[4], bf_[4];
    #pragma unroll
    for (int mt = 0; mt < 4; ++mt)
      af[mt] = *(const bf16x8*)&As[(woffM + mt*16 + (lane & 15))*32 + (lane >> 4)*8];
    #pragma unroll
    for (int nt = 0; nt < 4; ++nt)
      bf_[nt] = *(const bf16x8*)&Bs[(woffN + nt*16 + (lane & 15))*32 + (lane >> 4)*8];
    #pragma unroll
    for (int mt = 0; mt < 4; ++mt)
      #pragma unroll
      for (int nt = 0; nt < 4; ++nt)
        acc[mt][nt] = __builtin_amdgcn_mfma_f32_16x16x32_bf16(af[mt], bf_[nt], acc[mt][nt], 0, 0, 0);
  }
  const int col = lane & 15, lq = lane >> 4;
  #pragma unroll
  for (int nt = 0; nt < 4; ++nt){
    float bv = bias[n0 + woffN + nt*16 + col];
    #pragma unroll
    for (int mt = 0; mt < 4; ++mt)
      #pragma unroll
      for (int r = 0; r < 4; ++r){
        int grow = m0 + woffM + mt*16 + lq*4 + r;
        int gcol = n0 + woffN + nt*16 + col;
        C[(size_t)grow*G3 + gcol] = f2bf(acc[mt][nt][r] + bv);
      }
  }
}

// ---- block-local GRU layer. 16 blocks x 256 threads (4 waves).
// Block bid: batch rows bid*16..+15. Wave w: h-cols w*128..+127 (8 tiles), all 3 gates.
// h lives in block LDS (single buffer; the post-MFMA barrier separates read/write).
// Whh streamed from L2 (per-wave-contiguous frags); gi prefetched to LDS per step.
template<int LAST>
__global__ __launch_bounds__(256, 1) void kgru(
    const unsigned short* __restrict__ Wp, const float* __restrict__ bhh,
    const unsigned short* __restrict__ gi,
    unsigned short* __restrict__ hist, float* __restrict__ x2f){
  const int b0 = blockIdx.x * 16;
  const int tid = threadIdx.x;
  const int w = tid >> 6, lane = tid & 63;
  const int c = lane & 15, lq = lane >> 4;
  __shared__ __align__(16) unsigned short hbuf[16*512];    // 16KB h state
  __shared__ __align__(16) unsigned short gil[16*1536];    // 48KB gi tile

  float bh[3][8];
  #pragma unroll
  for (int g = 0; g < 3; ++g)
    #pragma unroll
    for (int ct = 0; ct < 8; ++ct)
      bh[g][ct] = bhh[g*512 + w*128 + ct*16 + c];
  float h_old[8][4];
  #pragma unroll
  for (int ct = 0; ct < 8; ++ct)
    #pragma unroll
    for (int r = 0; r < 4; ++r) h_old[ct][r] = 0.f;

  const unsigned short* wseg = Wp + (size_t)w*196608 + lane*8;

  #pragma unroll 1
  for (int t = 0; t < TT; ++t){
    // 1. issue gi(t) staging: 48KB contiguous, 12 chunks/wave, linear LDS dest
    {
      const unsigned short* gsrc = gi + ((size_t)t*256 + b0)*G3;
      #pragma unroll
      for (int j = 0; j < 12; ++j){
        int chunk = w*12 + j;
        gl_lds16(gsrc + chunk*512 + lane*8, (void*)&gil[chunk*512]);
      }
    }
    // 2. h-MFMA: A = h(t-1) from LDS, B = Whh streamed from L2 (same addrs every t)
    f32x4 acc[3][8] = {};
    if (t > 0){
      #pragma unroll
      for (int ks = 0; ks < 16; ++ks){
        bf16x8 af = *(const bf16x8*)((const char*)hbuf + c*1024 + (((ks*4 + lq) ^ (c & 7)) << 4));
        #pragma unroll
        for (int g = 0; g < 3; ++g)
          #pragma unroll
          for (int ct = 0; ct < 8; ++ct){
            bf16x8 bw = *(const bf16x8*)(wseg + (size_t)((g*8 + ct)*16 + ks)*512);
            acc[g][ct] = __builtin_amdgcn_mfma_f32_16x16x32_bf16(af, bw, acc[g][ct], 0, 0, 0);
          }
      }
    }
    // 3. gi staged (vmcnt) + all waves done reading hbuf
    asm volatile("s_waitcnt vmcnt(0)" ::: "memory");
    __syncthreads();
    // 4. gates (in-lane) + 5. write h(t) to LDS + stream outputs
    #pragma unroll
    for (int ct = 0; ct < 8; ++ct){
      int col = w*128 + ct*16 + c;
      #pragma unroll
      for (int r = 0; r < 4; ++r){
        int row = lq*4 + r;
        float gr = bf2f(gil[row*G3 + col]);
        float gz = bf2f(gil[row*G3 + 512 + col]);
        float gn = bf2f(gil[row*G3 + 1024 + col]);
        float rr = 1.f/(1.f + __expf(-(gr + acc[0][ct][r] + bh[0][ct])));
        float zz = 1.f/(1.f + __expf(-(gz + acc[1][ct][r] + bh[1][ct])));
        float np = gn + rr*(acc[2][ct][r] + bh[2][ct]);
        float ee = __expf(2.f*np);
        float nn = 1.f - 2.f/(ee + 1.f);
        float hn = (1.f - zz)*nn + zz*h_old[ct][r];
        h_old[ct][r] = hn;
        unsigned short hv = f2bf(hn);
        *(unsigned short*)((char*)hbuf + row*1024 + (((col >> 3) ^ (row & 7)) << 4)
                           + (col & 7)*2) = hv;
        if (!LAST) hist[((size_t)t*256 + b0 + row)*512 + col] = hv;
        else       x2f [((size_t)t*256 + b0 + row)*512 + col] = hn;
      }
    }
    __syncthreads();   // h(t) complete before next step's MFMA
  }
}

// ---- final FC in f32: logits[b][t][64] = x2f[(t,b)][512] @ fcwt + fc_b
__global__ __launch_bounds__(256) void kfc(const float* __restrict__ x,
    const float* __restrict__ wt, const float* __restrict__ fcb, float* __restrict__ out){
  __shared__ __align__(16) float xs[16*512];
  const int m0 = blockIdx.x*16;   // grid 2048
  for (int c = threadIdx.x; c < 2048; c += 256){
    int row = c >> 7, o = c & 127;
    *(f32x4*)&xs[row*512 + o*4] = *(const f32x4*)(x + (size_t)(m0+row)*512 + o*4);
  }
  __syncthreads();
  const int colv = threadIdx.x & 63, rq = threadIdx.x >> 6;
  float a0 = 0.f, a1 = 0.f, a2 = 0.f, a3 = 0.f;
  const float* x0p = xs + (rq*4 + 0)*512;
  const float* x1p = xs + (rq*4 + 1)*512;
  const float* x2p = xs + (rq*4 + 2)*512;
  const float* x3p = xs + (rq*4 + 3)*512;
  #pragma unroll 8
  for (int k = 0; k < 512; ++k){
    float w = wt[k*64 + colv];
    a0 += w * x0p[k]; a1 += w * x1p[k]; a2 += w * x2p[k]; a3 += w * x3p[k];
  }
  float bv = fcb[colv];
  float av[4] = {a0, a1, a2, a3};
  #pragma unroll
  for (int j = 0; j < 4; ++j){
    int m = m0 + rq*4 + j;
    int b = m & 255, t = m >> 8;               // (t,b) -> [b][t][64]
    out[((size_t)b*128 + t)*64 + colv] = av[j] + bv;
  }
}

extern "C" void kernel_launch(void* const* d_in, const int* in_sizes, int n_in,
                              void* d_out, int out_size, void* d_ws, size_t ws_size,
                              hipStream_t stream){
  const float* latent = (const float*)d_in[0];
  const float* enth   = (const float*)d_in[1];
  const int*   inp    = (const int*)d_in[2];
  const float* emb    = (const float*)d_in[3];
  const float* Wih0   = (const float*)d_in[4];
  const float* Whh0   = (const float*)d_in[5];
  const float* bih0   = (const float*)d_in[6];
  const float* bhh0   = (const float*)d_in[7];
  const float* Wih1   = (const float*)d_in[8];
  const float* Whh1   = (const float*)d_in[9];
  const float* bih1   = (const float*)d_in[10];
  const float* bhh1   = (const float*)d_in[11];
  const float* Wih2   = (const float*)d_in[12];
  const float* Whh2   = (const float*)d_in[13];
  const float* bih2   = (const float*)d_in[14];
  const float* bhh2   = (const float*)d_in[15];
  const float* fcW    = (const float*)d_in[16];
  const float* fcb    = (const float*)d_in[17];

  char* ws = (char*)d_ws;
  constexpr size_t OFF_HIST = 4096;
  constexpr size_t OFF_X0   = OFF_HIST + (size_t)32768*512*2;        // 32MB hist
  constexpr size_t OFF_X2F  = OFF_X0   + (size_t)32768*192*2;
  constexpr size_t OFF_WHP  = OFF_X2F  + (size_t)32768*512*4;
  constexpr size_t OFF_WIH0 = OFF_WHP  + (size_t)3*1536*512*2;
  constexpr size_t OFF_WIH1 = OFF_WIH0 + (size_t)1536*192*2;
  constexpr size_t OFF_WIH2 = OFF_WIH1 + (size_t)1536*512*2;
  constexpr size_t OFF_FCWT = OFF_WIH2 + (size_t)1536*512*2;
  constexpr size_t OFF_GI   = OFF_FCWT + (size_t)512*64*4;

  unsigned short* hist  = (unsigned short*)(ws + OFF_HIST);
  unsigned short* x0    = (unsigned short*)(ws + OFF_X0);
  float* x2f            = (float*)(ws + OFF_X2F);
  unsigned short* whp0  = (unsigned short*)(ws + OFF_WHP);
  unsigned short* whp1  = whp0 + (size_t)1536*512;
  unsigned short* whp2  = whp1 + (size_t)1536*512;
  unsigned short* wih0p = (unsigned short*)(ws + OFF_WIH0);
  unsigned short* wih1b = (unsigned short*)(ws + OFF_WIH1);
  unsigned short* wih2b = (unsigned short*)(ws + OFF_WIH2);
  float* fcwt           = (float*)(ws + OFF_FCWT);
  unsigned short* gi    = (unsigned short*)(ws + OFF_GI);

  kprep<<<13440, 256, 0, stream>>>(Wih1, Wih2, wih1b, wih2b,
                                   Whh0, Whh1, Whh2, whp0, whp1, whp2,
                                   Wih0, wih0p, fcW, fcwt);
  kx0  <<<8192, 192, 0, stream>>>(latent, enth, inp, emb, x0);

  kgemm<<<dim3(12,256), 256, 0, stream>>>(x0, wih0p, bih0, gi, 192);
  kgru<0><<<16, 256, 0, stream>>>(whp0, bhh0, gi, hist, x2f);
  kgemm<<<dim3(12,256), 256, 0, stream>>>(hist, wih1b, bih1, gi, 512);
  kgru<0><<<16, 256, 0, stream>>>(whp1, bhh1, gi, hist, x2f);
  kgemm<<<dim3(12,256), 256, 0, stream>>>(hist, wih2b, bih2, gi, 512);
  kgru<1><<<16, 256, 0, stream>>>(whp2, bhh2, gi, hist, x2f);
  kfc  <<<2048, 256, 0, stream>>>(x2f, fcwt, fcb, (float*)d_out);
}